// Round 1
// baseline (1854.881 us; speedup 1.0000x reference)
//
#include <hip/hip_runtime.h>
#include <math.h>

#define TOKENS 16384
#define DIM    768
#define EDIM   2304
#define NHEADS 12
#define DHEAD  64
#define NQKVW  (EDIM*DIM)   // 1769472
#define NOUTW  (DIM*DIM)    // 589824
#define LN_EPS 1e-5f

// ---------------- wave reduction helpers ----------------
__device__ __forceinline__ float wsum(float v){
#pragma unroll
  for(int m=1;m<64;m<<=1) v += __shfl_xor(v,m);
  return v;
}
__device__ __forceinline__ int wsumi(int v){
#pragma unroll
  for(int m=1;m<64;m<<=1) v += __shfl_xor(v,m);
  return v;
}
__device__ __forceinline__ unsigned wminu(unsigned v){
#pragma unroll
  for(int m=1;m<64;m<<=1){ unsigned o = __shfl_xor(v,m); v = (o<v)?o:v; }
  return v;
}

// ---------------- mean(|w|) reduction for both weight tensors ----------------
__global__ __launch_bounds__(256) void absmean_kernel(
    const float* __restrict__ w1, int n1,
    const float* __restrict__ w2, int n2,
    double* __restrict__ sums){
  int stride = gridDim.x*blockDim.x;
  int i0 = blockIdx.x*blockDim.x + threadIdx.x;
  float s1=0.f, s2=0.f;
  for(int i=i0;i<n1;i+=stride) s1 += fabsf(w1[i]);
  for(int i=i0;i<n2;i+=stride) s2 += fabsf(w2[i]);
  double d1=(double)s1, d2=(double)s2;
#pragma unroll
  for(int m=1;m<64;m<<=1){ d1 += __shfl_xor(d1,m); d2 += __shfl_xor(d2,m); }
  __shared__ double l1[4], l2[4];
  int w = threadIdx.x>>6;
  if((threadIdx.x&63)==0){ l1[w]=d1; l2[w]=d2; }
  __syncthreads();
  if(threadIdx.x==0){
    atomicAdd(&sums[0], l1[0]+l1[1]+l1[2]+l1[3]);
    atomicAdd(&sums[1], l2[0]+l2[1]+l2[2]+l2[3]);
  }
}

// ---------------- BitNet ternarize: clip(round(w/(s+1e-8)),-1,1)*s ----------------
__global__ __launch_bounds__(256) void ternarize_kernel(
    const float* __restrict__ w, int n,
    const double* __restrict__ sums, int idx,
    float* __restrict__ o){
  float s  = (float)(sums[idx]/(double)n);
  float sd = s + 1e-8f;
  int i = blockIdx.x*blockDim.x + threadIdx.x;
  if(i<n){
    float t = rintf(w[i]/sd);           // rint: round-half-even, matches np.round
    t = fminf(fmaxf(t,-1.f),1.f);
    o[i] = t*s;
  }
}

// ---------------- LayerNorm (optional) + quantile sparsify; one wave per token ----------------
// Exact k-th order statistics via MSB-first radix select on |x| bit patterns
// (non-negative float bits are order-preserving as uint32).
template<bool DO_LN>
__global__ __launch_bounds__(256) void ln_sparsify_kernel(
    const float* __restrict__ in,
    const float* __restrict__ gamma,
    const float* __restrict__ beta,
    const float* __restrict__ qp,
    float* __restrict__ out){
  int token = blockIdx.x*4 + (threadIdx.x>>6);
  int lane  = threadIdx.x & 63;
  const float* row = in + (size_t)token*DIM;
  float v[12];
#pragma unroll
  for(int g=0; g<3; ++g){
    float4 t = *(const float4*)(row + g*256 + lane*4);
    v[g*4+0]=t.x; v[g*4+1]=t.y; v[g*4+2]=t.z; v[g*4+3]=t.w;
  }
  float xn[12];
  if (DO_LN){
    float s=0.f;
#pragma unroll
    for(int i=0;i<12;i++) s += v[i];
    s = wsum(s);
    float mu = s*(1.f/768.f);
    float ss=0.f;
#pragma unroll
    for(int i=0;i<12;i++){ float d=v[i]-mu; ss += d*d; }
    ss = wsum(ss);
    float inv = 1.f/sqrtf(ss*(1.f/768.f) + LN_EPS);
#pragma unroll
    for(int g=0; g<3; ++g){
      float4 gm = *(const float4*)(gamma + g*256 + lane*4);
      float4 bt = *(const float4*)(beta  + g*256 + lane*4);
      xn[g*4+0] = (v[g*4+0]-mu)*inv*gm.x + bt.x;
      xn[g*4+1] = (v[g*4+1]-mu)*inv*gm.y + bt.y;
      xn[g*4+2] = (v[g*4+2]-mu)*inv*gm.z + bt.z;
      xn[g*4+3] = (v[g*4+3]-mu)*inv*gm.w + bt.w;
    }
  } else {
#pragma unroll
    for(int i=0;i<12;i++) xn[i]=v[i];
  }
  unsigned a[12];
#pragma unroll
  for(int i=0;i<12;i++) a[i] = __float_as_uint(fabsf(xn[i]));
  float q = *qp;
  float pos = q*767.f;
  int lo = (int)floorf(pos);
  lo = lo<0 ? 0 : (lo>767 ? 767 : lo);
  float frac = pos-(float)lo;
  // radix select: exact value of rank `lo` (0-based) among 768 elements
  unsigned prefix=0;
  int r = lo;
#pragma unroll 1
  for(int bit=30; bit>=0; --bit){
    unsigned cand = prefix | (1u<<bit);
    int c=0;
#pragma unroll
    for(int i=0;i<12;i++) c += (a[i]>=prefix && a[i]<cand) ? 1 : 0;
    c = wsumi(c);
    if(r>=c){ r-=c; prefix=cand; }
  }
  float f1 = __uint_as_float(prefix);
  float thr;
  if (frac>0.f && lo<767){
    // rank lo+1: duplicate-aware (== prefix if enough ties, else min of strictly-greater)
    int cle=0;
#pragma unroll
    for(int i=0;i<12;i++) cle += (a[i]<=prefix)?1:0;
    cle = wsumi(cle);
    unsigned mn=0xFFFFFFFFu;
#pragma unroll
    for(int i=0;i<12;i++){ if(a[i]>prefix && a[i]<mn) mn=a[i]; }
    mn = wminu(mn);
    float f2 = (cle>=lo+2) ? f1 : __uint_as_float(mn);
    // numpy _lerp (t>=0.5 uses the b-anchored form)
    thr = (frac>=0.5f) ? f2-(f2-f1)*(1.f-frac) : f1+(f2-f1)*frac;
  } else thr=f1;
  float* orow = out + (size_t)token*DIM;
#pragma unroll
  for(int g=0; g<3; ++g){
    float4 t;
    t.x = (fabsf(xn[g*4+0])>=thr)?xn[g*4+0]:0.f;
    t.y = (fabsf(xn[g*4+1])>=thr)?xn[g*4+1]:0.f;
    t.z = (fabsf(xn[g*4+2])>=thr)?xn[g*4+2]:0.f;
    t.w = (fabsf(xn[g*4+3])>=thr)?xn[g*4+3]:0.f;
    *(float4*)(orow + g*256 + lane*4) = t;
  }
}

// ---------------- fp32 GEMM: C[M][N] = A[M][K] * Bw[N][K]^T (+bias) ----------------
// 128x128 tile, BK=16, 256 threads, 8x8 register micro-tile.
template<bool BIAS>
__global__ __launch_bounds__(256) void gemm_nt_kernel(
    const float* __restrict__ A,
    const float* __restrict__ Bw,
    const float* __restrict__ bias,
    float* __restrict__ C,
    int M, int Nn, int K){
  __shared__ float As[16][132];
  __shared__ float Bs[16][132];
  int bm = blockIdx.y*128;
  int bn = blockIdx.x*128;
  int tid = threadIdx.x;
  int tx = tid & 15, ty = tid >> 4;
  float acc[8][8];
#pragma unroll
  for(int i=0;i<8;i++)
#pragma unroll
    for(int j=0;j<8;j++) acc[i][j]=0.f;

  for(int k0=0;k0<K;k0+=16){
#pragma unroll
    for(int f=tid; f<512; f+=256){
      int rr = f>>2, kg=(f&3)<<2;
      float4 va = *(const float4*)(A  + (size_t)(bm+rr)*K + k0+kg);
      As[kg+0][rr]=va.x; As[kg+1][rr]=va.y; As[kg+2][rr]=va.z; As[kg+3][rr]=va.w;
      float4 vb = *(const float4*)(Bw + (size_t)(bn+rr)*K + k0+kg);
      Bs[kg+0][rr]=vb.x; Bs[kg+1][rr]=vb.y; Bs[kg+2][rr]=vb.z; Bs[kg+3][rr]=vb.w;
    }
    __syncthreads();
#pragma unroll
    for(int k=0;k<16;++k){
      float a8[8], b8[8];
      *(float4*)(a8+0) = *(const float4*)(&As[k][ty*8+0]);
      *(float4*)(a8+4) = *(const float4*)(&As[k][ty*8+4]);
      *(float4*)(b8+0) = *(const float4*)(&Bs[k][tx*8+0]);
      *(float4*)(b8+4) = *(const float4*)(&Bs[k][tx*8+4]);
#pragma unroll
      for(int i=0;i<8;i++)
#pragma unroll
        for(int j=0;j<8;j++)
          acc[i][j] = fmaf(a8[i], b8[j], acc[i][j]);
    }
    __syncthreads();
  }
#pragma unroll
  for(int i=0;i<8;i++){
    float4 o0, o1;
    o0.x=acc[i][0]; o0.y=acc[i][1]; o0.z=acc[i][2]; o0.w=acc[i][3];
    o1.x=acc[i][4]; o1.y=acc[i][5]; o1.z=acc[i][6]; o1.w=acc[i][7];
    if(BIAS){
      float4 b0 = *(const float4*)(bias + bn + tx*8);
      float4 b1 = *(const float4*)(bias + bn + tx*8 + 4);
      o0.x+=b0.x; o0.y+=b0.y; o0.z+=b0.z; o0.w+=b0.w;
      o1.x+=b1.x; o1.y+=b1.y; o1.z+=b1.z; o1.w+=b1.w;
    }
    float* cp = C + (size_t)(bm+ty*8+i)*Nn + bn + tx*8;
    *(float4*)cp     = o0;
    *(float4*)(cp+4) = o1;
  }
}

// ---------------- flash attention, fp32, one block per (qblock64, head, batch) ----------------
__global__ __launch_bounds__(256) void attention_kernel(
    const float* __restrict__ qkv, float* __restrict__ ao){
  __shared__ float Qs[64][68];   // [d][i], Q pre-scaled by 1/8
  __shared__ float KPs[64][68];  // [d][j] for K, then reused as [j][i] for P
  __shared__ float Vs[64][68];   // [j][d]
  int qb = blockIdx.x;
  int h  = blockIdx.y;
  int b  = blockIdx.z;
  int tid = threadIdx.x;
  int tx = tid & 15, ty = tid >> 4;
  const float* qbase = qkv + ((size_t)b*1024 + qb*64)*EDIM + h*DHEAD;
  const float* kbase = qkv + (size_t)b*1024*EDIM + 768 + h*DHEAD;
  const float* vbase = kbase + 768;

#pragma unroll
  for(int f=tid; f<1024; f+=256){
    int i = f>>4, dg=(f&15)*4;
    float4 t = *(const float4*)(qbase + (size_t)i*EDIM + dg);
    Qs[dg+0][i]=t.x*0.125f; Qs[dg+1][i]=t.y*0.125f;
    Qs[dg+2][i]=t.z*0.125f; Qs[dg+3][i]=t.w*0.125f;
  }

  float o[4][4];
  float m[4], l[4];
#pragma unroll
  for(int r=0;r<4;r++){
    m[r]=-INFINITY; l[r]=0.f;
#pragma unroll
    for(int c=0;c<4;c++) o[r][c]=0.f;
  }

  for(int kt=0; kt<16; ++kt){
    __syncthreads();   // prior PV reads of KPs/Vs complete
#pragma unroll
    for(int f=tid; f<1024; f+=256){
      int j=f>>4, dg=(f&15)*4;
      float4 t = *(const float4*)(kbase + (size_t)(kt*64+j)*EDIM + dg);
      KPs[dg+0][j]=t.x; KPs[dg+1][j]=t.y; KPs[dg+2][j]=t.z; KPs[dg+3][j]=t.w;
      float4 u = *(const float4*)(vbase + (size_t)(kt*64+j)*EDIM + dg);
      *(float4*)(&Vs[j][dg]) = u;
    }
    __syncthreads();
    float s[4][4];
#pragma unroll
    for(int r=0;r<4;r++)
#pragma unroll
      for(int c=0;c<4;c++) s[r][c]=0.f;
#pragma unroll 8
    for(int d=0;d<64;++d){
      float a4[4], b4[4];
      *(float4*)a4 = *(const float4*)(&Qs[d][ty*4]);
      *(float4*)b4 = *(const float4*)(&KPs[d][tx*4]);
#pragma unroll
      for(int r=0;r<4;r++)
#pragma unroll
        for(int c=0;c<4;c++) s[r][c] = fmaf(a4[r], b4[c], s[r][c]);
    }
    // online softmax update (rows spread across the 16-lane tx group)
    float p[4][4];
#pragma unroll
    for(int r=0;r<4;r++){
      float rm = fmaxf(fmaxf(s[r][0],s[r][1]), fmaxf(s[r][2],s[r][3]));
#pragma unroll
      for(int msk=1; msk<16; msk<<=1) rm = fmaxf(rm, __shfl_xor(rm,msk));
      float mn = fmaxf(m[r], rm);
      float alpha = __expf(m[r]-mn);
      m[r] = mn;
      float rs = 0.f;
#pragma unroll
      for(int c=0;c<4;c++){ p[r][c] = __expf(s[r][c]-mn); rs += p[r][c]; }
#pragma unroll
      for(int msk=1; msk<16; msk<<=1) rs += __shfl_xor(rs,msk);
      l[r] = l[r]*alpha + rs;
#pragma unroll
      for(int c=0;c<4;c++) o[r][c] *= alpha;
    }
    __syncthreads();   // all S reads of KPs done before overwrite with P
#pragma unroll
    for(int r=0;r<4;r++)
#pragma unroll
      for(int c=0;c<4;c++) KPs[tx*4+c][ty*4+r] = p[r][c];
    __syncthreads();
#pragma unroll 8
    for(int j=0;j<64;++j){
      float pa[4], vb[4];
      *(float4*)pa = *(const float4*)(&KPs[j][ty*4]);
      *(float4*)vb = *(const float4*)(&Vs[j][tx*4]);
#pragma unroll
      for(int r=0;r<4;r++)
#pragma unroll
        for(int c=0;c<4;c++) o[r][c] = fmaf(pa[r], vb[c], o[r][c]);
    }
  }
#pragma unroll
  for(int r=0;r<4;r++){
    float il = 1.f/l[r];
    size_t t = (size_t)(b*1024 + qb*64 + ty*4 + r)*DIM + h*DHEAD + tx*4;
    float4 o4;
    o4.x=o[r][0]*il; o4.y=o[r][1]*il; o4.z=o[r][2]*il; o4.w=o[r][3]*il;
    *(float4*)(ao + t) = o4;
  }
}

extern "C" void kernel_launch(void* const* d_in, const int* in_sizes, int n_in,
                              void* d_out, int out_size, void* d_ws, size_t ws_size,
                              hipStream_t stream){
  const float* x      = (const float*)d_in[0];
  const float* gamma  = (const float*)d_in[1];
  const float* beta   = (const float*)d_in[2];
  const float* w_qkv  = (const float*)d_in[3];
  const float* w_out  = (const float*)d_in[4];
  const float* b_out  = (const float*)d_in[5];
  const float* spars  = (const float*)d_in[6];
  float* out = (float*)d_out;

  // workspace layout (floats): [sums:4][wq_qkv][wq_out][xs][qkv][ao]  ~261 MB
  double* sums  = (double*)d_ws;
  float* wq_qkv = (float*)d_ws + 4;
  float* wq_out = wq_qkv + NQKVW;
  float* xs     = wq_out + NOUTW;                 // reused for 2nd sparsify output
  float* qkvb   = xs + (size_t)TOKENS*DIM;
  float* ao     = qkvb + (size_t)TOKENS*EDIM;

  hipMemsetAsync(d_ws, 0, 16, stream);  // zero the two double accumulators
  absmean_kernel<<<1024,256,0,stream>>>(w_qkv, NQKVW, w_out, NOUTW, sums);
  ternarize_kernel<<<(NQKVW+255)/256,256,0,stream>>>(w_qkv, NQKVW, sums, 0, wq_qkv);
  ternarize_kernel<<<(NOUTW+255)/256,256,0,stream>>>(w_out, NOUTW, sums, 1, wq_out);
  ln_sparsify_kernel<true><<<TOKENS/4,256,0,stream>>>(x, gamma, beta, spars, xs);
  gemm_nt_kernel<false><<<dim3(EDIM/128, TOKENS/128),256,0,stream>>>(
      xs, wq_qkv, nullptr, qkvb, TOKENS, EDIM, DIM);
  attention_kernel<<<dim3(16,NHEADS,16),256,0,stream>>>(qkvb, ao);
  ln_sparsify_kernel<false><<<TOKENS/4,256,0,stream>>>(ao, nullptr, nullptr, spars, xs);
  gemm_nt_kernel<true><<<dim3(DIM/128, TOKENS/128),256,0,stream>>>(
      xs, wq_out, b_out, out, TOKENS, DIM, DIM);
}

// Round 3
// 1322.704 us; speedup vs baseline: 1.4023x; 1.4023x over previous
//
#include <hip/hip_runtime.h>
#include <math.h>

#define TOKENS 16384
#define DIM    768
#define EDIM   2304
#define NHEADS 12
#define DHEAD  64
#define NQKVW  (EDIM*DIM)   // 1769472
#define NOUTW  (DIM*DIM)    // 589824
#define LN_EPS 1e-5f

typedef __bf16 bf16x8 __attribute__((ext_vector_type(8)));
typedef float f32x4 __attribute__((ext_vector_type(4)));
typedef unsigned short u16x8 __attribute__((ext_vector_type(8)));

// ---------------- wave reduction helpers ----------------
__device__ __forceinline__ float wsum(float v){
#pragma unroll
  for(int m=1;m<64;m<<=1) v += __shfl_xor(v,m);
  return v;
}
__device__ __forceinline__ int wsumi(int v){
#pragma unroll
  for(int m=1;m<64;m<<=1) v += __shfl_xor(v,m);
  return v;
}
__device__ __forceinline__ unsigned wminu(unsigned v){
#pragma unroll
  for(int m=1;m<64;m<<=1){ unsigned o = __shfl_xor(v,m); v = (o<v)?o:v; }
  return v;
}

// RNE float -> bf16 bits
__device__ __forceinline__ unsigned short bf_rne(float x){
  unsigned u = __float_as_uint(x);
  unsigned r = (u + 0x7FFFu + ((u>>16)&1u)) >> 16;
  return (unsigned short)r;
}
// split x = h + l (+ ~2^-17 residual), h,l bf16
__device__ __forceinline__ void split_bf(float x, unsigned short& h, unsigned short& l){
  h = bf_rne(x);
  float hf = __uint_as_float(((unsigned)h)<<16);
  l = bf_rne(x - hf);
}

// ---------------- mean(|w|) reduction for both weight tensors ----------------
__global__ __launch_bounds__(256) void absmean_kernel(
    const float* __restrict__ w1, int n1,
    const float* __restrict__ w2, int n2,
    double* __restrict__ sums){
  int stride = gridDim.x*blockDim.x;
  int i0 = blockIdx.x*blockDim.x + threadIdx.x;
  float s1=0.f, s2=0.f;
  for(int i=i0;i<n1;i+=stride) s1 += fabsf(w1[i]);
  for(int i=i0;i<n2;i+=stride) s2 += fabsf(w2[i]);
  double d1=(double)s1, d2=(double)s2;
#pragma unroll
  for(int m=1;m<64;m<<=1){ d1 += __shfl_xor(d1,m); d2 += __shfl_xor(d2,m); }
  __shared__ double l1[4], l2[4];
  int w = threadIdx.x>>6;
  if((threadIdx.x&63)==0){ l1[w]=d1; l2[w]=d2; }
  __syncthreads();
  if(threadIdx.x==0){
    atomicAdd(&sums[0], l1[0]+l1[1]+l1[2]+l1[3]);
    atomicAdd(&sums[1], l2[0]+l2[1]+l2[2]+l2[3]);
  }
}

// ---------------- BitNet ternarize ----------------
__global__ __launch_bounds__(256) void ternarize_kernel(
    const float* __restrict__ w, int n,
    const double* __restrict__ sums, int idx,
    float* __restrict__ o){
  float s  = (float)(sums[idx]/(double)n);
  float sd = s + 1e-8f;
  int i = blockIdx.x*blockDim.x + threadIdx.x;
  if(i<n){
    float t = rintf(w[i]/sd);
    t = fminf(fmaxf(t,-1.f),1.f);
    o[i] = t*s;
  }
}

// ---------------- LayerNorm (optional) + quantile sparsify; one wave per token ----------------
template<bool DO_LN>
__global__ __launch_bounds__(256) void ln_sparsify_kernel(
    const float* __restrict__ in,
    const float* __restrict__ gamma,
    const float* __restrict__ beta,
    const float* __restrict__ qp,
    float* __restrict__ out){
  int token = blockIdx.x*4 + (threadIdx.x>>6);
  int lane  = threadIdx.x & 63;
  const float* row = in + (size_t)token*DIM;
  float v[12];
#pragma unroll
  for(int g=0; g<3; ++g){
    float4 t = *(const float4*)(row + g*256 + lane*4);
    v[g*4+0]=t.x; v[g*4+1]=t.y; v[g*4+2]=t.z; v[g*4+3]=t.w;
  }
  float xn[12];
  if (DO_LN){
    float s=0.f;
#pragma unroll
    for(int i=0;i<12;i++) s += v[i];
    s = wsum(s);
    float mu = s*(1.f/768.f);
    float ss=0.f;
#pragma unroll
    for(int i=0;i<12;i++){ float d=v[i]-mu; ss += d*d; }
    ss = wsum(ss);
    float inv = 1.f/sqrtf(ss*(1.f/768.f) + LN_EPS);
#pragma unroll
    for(int g=0; g<3; ++g){
      float4 gm = *(const float4*)(gamma + g*256 + lane*4);
      float4 bt = *(const float4*)(beta  + g*256 + lane*4);
      xn[g*4+0] = (v[g*4+0]-mu)*inv*gm.x + bt.x;
      xn[g*4+1] = (v[g*4+1]-mu)*inv*gm.y + bt.y;
      xn[g*4+2] = (v[g*4+2]-mu)*inv*gm.z + bt.z;
      xn[g*4+3] = (v[g*4+3]-mu)*inv*gm.w + bt.w;
    }
  } else {
#pragma unroll
    for(int i=0;i<12;i++) xn[i]=v[i];
  }
  unsigned a[12];
#pragma unroll
  for(int i=0;i<12;i++) a[i] = __float_as_uint(fabsf(xn[i]));
  float q = *qp;
  float pos = q*767.f;
  int lo = (int)floorf(pos);
  lo = lo<0 ? 0 : (lo>767 ? 767 : lo);
  float frac = pos-(float)lo;
  unsigned prefix=0;
  int r = lo;
#pragma unroll 1
  for(int bit=30; bit>=0; --bit){
    unsigned cand = prefix | (1u<<bit);
    int c=0;
#pragma unroll
    for(int i=0;i<12;i++) c += (a[i]>=prefix && a[i]<cand) ? 1 : 0;
    c = wsumi(c);
    if(r>=c){ r-=c; prefix=cand; }
  }
  float f1 = __uint_as_float(prefix);
  float thr;
  if (frac>0.f && lo<767){
    int cle=0;
#pragma unroll
    for(int i=0;i<12;i++) cle += (a[i]<=prefix)?1:0;
    cle = wsumi(cle);
    unsigned mn=0xFFFFFFFFu;
#pragma unroll
    for(int i=0;i<12;i++){ if(a[i]>prefix && a[i]<mn) mn=a[i]; }
    mn = wminu(mn);
    float f2 = (cle>=lo+2) ? f1 : __uint_as_float(mn);
    thr = (frac>=0.5f) ? f2-(f2-f1)*(1.f-frac) : f1+(f2-f1)*frac;
  } else thr=f1;
  float* orow = out + (size_t)token*DIM;
#pragma unroll
  for(int g=0; g<3; ++g){
    float4 t;
    t.x = (fabsf(xn[g*4+0])>=thr)?xn[g*4+0]:0.f;
    t.y = (fabsf(xn[g*4+1])>=thr)?xn[g*4+1]:0.f;
    t.z = (fabsf(xn[g*4+2])>=thr)?xn[g*4+2]:0.f;
    t.w = (fabsf(xn[g*4+3])>=thr)?xn[g*4+3]:0.f;
    *(float4*)(orow + g*256 + lane*4) = t;
  }
}

// ---------------- fp32 GEMM core macro-ish helpers ----------------
// C[M][N] = A[M][K] * Bw[N][K]^T; 128x128 tile, BK=16, 256 threads, 8x8 micro-tile.

// Final projection GEMM with bias, fp32 out.
__global__ __launch_bounds__(256) void gemm_out_kernel(
    const float* __restrict__ A,
    const float* __restrict__ Bw,
    const float* __restrict__ bias,
    float* __restrict__ C,
    int M, int Nn, int K){
  __shared__ float As[16][132];
  __shared__ float Bs[16][132];
  int bm = blockIdx.y*128;
  int bn = blockIdx.x*128;
  int tid = threadIdx.x;
  int tx = tid & 15, ty = tid >> 4;
  float acc[8][8];
#pragma unroll
  for(int i=0;i<8;i++)
#pragma unroll
    for(int j=0;j<8;j++) acc[i][j]=0.f;

  for(int k0=0;k0<K;k0+=16){
#pragma unroll
    for(int f=tid; f<512; f+=256){
      int rr = f>>2, kg=(f&3)<<2;
      float4 va = *(const float4*)(A  + (size_t)(bm+rr)*K + k0+kg);
      As[kg+0][rr]=va.x; As[kg+1][rr]=va.y; As[kg+2][rr]=va.z; As[kg+3][rr]=va.w;
      float4 vb = *(const float4*)(Bw + (size_t)(bn+rr)*K + k0+kg);
      Bs[kg+0][rr]=vb.x; Bs[kg+1][rr]=vb.y; Bs[kg+2][rr]=vb.z; Bs[kg+3][rr]=vb.w;
    }
    __syncthreads();
#pragma unroll
    for(int k=0;k<16;++k){
      float a8[8], b8[8];
      *(float4*)(a8+0) = *(const float4*)(&As[k][ty*8+0]);
      *(float4*)(a8+4) = *(const float4*)(&As[k][ty*8+4]);
      *(float4*)(b8+0) = *(const float4*)(&Bs[k][tx*8+0]);
      *(float4*)(b8+4) = *(const float4*)(&Bs[k][tx*8+4]);
#pragma unroll
      for(int i=0;i<8;i++)
#pragma unroll
        for(int j=0;j<8;j++)
          acc[i][j] = fmaf(a8[i], b8[j], acc[i][j]);
    }
    __syncthreads();
  }
#pragma unroll
  for(int i=0;i<8;i++){
    float4 o0, o1;
    o0.x=acc[i][0]; o0.y=acc[i][1]; o0.z=acc[i][2]; o0.w=acc[i][3];
    o1.x=acc[i][4]; o1.y=acc[i][5]; o1.z=acc[i][6]; o1.w=acc[i][7];
    float4 b0 = *(const float4*)(bias + bn + tx*8);
    float4 b1 = *(const float4*)(bias + bn + tx*8 + 4);
    o0.x+=b0.x; o0.y+=b0.y; o0.z+=b0.z; o0.w+=b0.w;
    o1.x+=b1.x; o1.y+=b1.y; o1.z+=b1.z; o1.w+=b1.w;
    float* cp = C + (size_t)(bm+ty*8+i)*Nn + bn + tx*8;
    *(float4*)cp     = o0;
    *(float4*)(cp+4) = o1;
  }
}

// QKV GEMM: fp32 core; epilogue splits fp32 acc into bf16 hi/lo buffers.
// Q cols [0,768): scaled 0.125 -> qh/ql[tok][e]
// K cols [768,1536): -> kh/kl[tok][e-768]
// V cols [1536,2304): transposed -> vth/vtl[((b*12+h)*64+d)*1024 + t]
__global__ __launch_bounds__(256) void gemm_qkv_kernel(
    const float* __restrict__ A,
    const float* __restrict__ Bw,
    unsigned short* __restrict__ qh, unsigned short* __restrict__ ql,
    unsigned short* __restrict__ kh, unsigned short* __restrict__ kl,
    unsigned short* __restrict__ vth, unsigned short* __restrict__ vtl){
  __shared__ float As[16][132];
  __shared__ float Bs[16][132];
  const int K = DIM;
  int bm = blockIdx.y*128;
  int bn = blockIdx.x*128;
  int tid = threadIdx.x;
  int tx = tid & 15, ty = tid >> 4;
  float acc[8][8];
#pragma unroll
  for(int i=0;i<8;i++)
#pragma unroll
    for(int j=0;j<8;j++) acc[i][j]=0.f;

  for(int k0=0;k0<K;k0+=16){
#pragma unroll
    for(int f=tid; f<512; f+=256){
      int rr = f>>2, kg=(f&3)<<2;
      float4 va = *(const float4*)(A  + (size_t)(bm+rr)*K + k0+kg);
      As[kg+0][rr]=va.x; As[kg+1][rr]=va.y; As[kg+2][rr]=va.z; As[kg+3][rr]=va.w;
      float4 vb = *(const float4*)(Bw + (size_t)(bn+rr)*K + k0+kg);
      Bs[kg+0][rr]=vb.x; Bs[kg+1][rr]=vb.y; Bs[kg+2][rr]=vb.z; Bs[kg+3][rr]=vb.w;
    }
    __syncthreads();
#pragma unroll
    for(int k=0;k<16;++k){
      float a8[8], b8[8];
      *(float4*)(a8+0) = *(const float4*)(&As[k][ty*8+0]);
      *(float4*)(a8+4) = *(const float4*)(&As[k][ty*8+4]);
      *(float4*)(b8+0) = *(const float4*)(&Bs[k][tx*8+0]);
      *(float4*)(b8+4) = *(const float4*)(&Bs[k][tx*8+4]);
#pragma unroll
      for(int i=0;i<8;i++)
#pragma unroll
        for(int j=0;j<8;j++)
          acc[i][j] = fmaf(a8[i], b8[j], acc[i][j]);
    }
    __syncthreads();
  }
  // ---- epilogue: per-block uniform region (bn multiples of 128; 768/1536 are too) ----
  if (bn < 1536){
    const bool isQ = bn < 768;
    const float sc = isQ ? 0.125f : 1.f;
    unsigned short* dh = isQ ? qh : kh;
    unsigned short* dl = isQ ? ql : kl;
    int cb = isQ ? bn : (bn-768);
#pragma unroll
    for(int i=0;i<8;i++){
      u16x8 hv, lv;
#pragma unroll
      for(int j=0;j<8;j++){
        unsigned short hh, ll;
        split_bf(acc[i][j]*sc, hh, ll);
        hv[j]=hh; lv[j]=ll;
      }
      size_t off = (size_t)(bm+ty*8+i)*768 + cb + tx*8;
      *(u16x8*)(dh + off) = hv;
      *(u16x8*)(dl + off) = lv;
    }
  } else {
    int b  = bm >> 10;               // 1024 tokens per batch; bm%1024 within
    int t0 = (bm & 1023) + ty*8;
    int h0 = (bn - 1536) >> 6;       // block spans heads h0, h0+1
#pragma unroll
    for(int j=0;j<8;j++){
      int col = tx*8 + j;            // 0..127 within block
      int h = h0 + (col>>6);
      int d = col & 63;
      u16x8 hv, lv;
#pragma unroll
      for(int i=0;i<8;i++){
        unsigned short hh, ll;
        split_bf(acc[i][j], hh, ll);
        hv[i]=hh; lv[i]=ll;
      }
      size_t off = ((size_t)(b*NHEADS + h)*64 + d)*1024 + t0;
      *(u16x8*)(vth + off) = hv;
      *(u16x8*)(vtl + off) = lv;
    }
  }
}

// ---------------- MFMA flash attention ----------------
// Swapped QK^T: S^T[kv][q] = mfma(A=K, B=Q^T); PV as out^T[d][q] = mfma(A=V^T, B=P^T).
// 4 waves x 16 q-rows = 64-q block; kv tiles of 64.
// QK: 3-term split (Kh*Qh + Kh*Ql + Kl*Qh); PV: 4-term (Vh*Ph + Vh*Pl + Vl*Ph + Vl*Pl).
#define LDSW(row,c16) ((((row)*8 + ((c16) ^ ((row)&7))))*16)

__global__ __launch_bounds__(256) void attn_mfma_kernel(
    const unsigned short* __restrict__ qh, const unsigned short* __restrict__ ql,
    const unsigned short* __restrict__ kh, const unsigned short* __restrict__ kl,
    const unsigned short* __restrict__ vh, const unsigned short* __restrict__ vl,
    float* __restrict__ ao){
  __shared__ char lds[32768];   // [Kh|Kl|Vh|Vl] x 8KB, swizzled 64x64 bf16 tiles
  const int qb=blockIdx.x, h=blockIdx.y, b=blockIdx.z;
  const int tid=threadIdx.x, w=tid>>6, l=tid&63, lq=l&15, g=l>>4;

  const int qtok = b*1024 + qb*64 + w*16 + lq;
  bf16x8 qhf[2], qlf[2];
  {
    const size_t qo = (size_t)qtok*768 + h*64 + g*8;
    qhf[0] = *(const bf16x8*)(qh + qo);
    qhf[1] = *(const bf16x8*)(qh + qo + 32);
    qlf[0] = *(const bf16x8*)(ql + qo);
    qlf[1] = *(const bf16x8*)(ql + qo + 32);
  }
  const f32x4 zero4 = {0.f,0.f,0.f,0.f};
  f32x4 o[4];
#pragma unroll
  for(int mt=0;mt<4;mt++) o[mt]=zero4;
  float ms = -INFINITY, ls = 0.f;

  for(int kt=0; kt<16; ++kt){
    __syncthreads();
    // ---- stage Kh,Kl,Vh,Vl tiles into swizzled LDS ----
#pragma unroll
    for(int m=0;m<4;m++){
      const unsigned short* src = (m==0)?kh:(m==1)?kl:(m==2)?vh:vl;
#pragma unroll
      for(int half=0; half<2; half++){
        int a = half*256 + tid;              // slot 0..511
        int row = a>>3;
        int c16 = (a&7)^(row&7);
        size_t goff = (m<2)
          ? ((size_t)(b*1024 + kt*64 + row)*768 + h*64 + c16*8)
          : (((size_t)(b*NHEADS + h)*64 + row)*1024 + kt*64 + c16*8);
        u16x8 v = *(const u16x8*)(src + goff);
        *(u16x8*)(lds + m*8192 + a*16) = v;
      }
    }
    __syncthreads();
    // ---- S^T = K . Q^T  (3-term split) ----
    f32x4 s[4];
#pragma unroll
    for(int mt=0;mt<4;mt++) s[mt]=zero4;
#pragma unroll
    for(int kc=0;kc<2;kc++){
#pragma unroll
      for(int mt=0;mt<4;mt++){
        bf16x8 ka = *(const bf16x8*)(lds + 0*8192 + LDSW(16*mt+lq, 4*kc+g));
        bf16x8 kb = *(const bf16x8*)(lds + 1*8192 + LDSW(16*mt+lq, 4*kc+g));
        s[mt] = __builtin_amdgcn_mfma_f32_16x16x32_bf16(ka, qhf[kc], s[mt], 0,0,0);
        s[mt] = __builtin_amdgcn_mfma_f32_16x16x32_bf16(ka, qlf[kc], s[mt], 0,0,0);
        s[mt] = __builtin_amdgcn_mfma_f32_16x16x32_bf16(kb, qhf[kc], s[mt], 0,0,0);
      }
    }
    // ---- online softmax (per q = lane&15; kv spread over regs + lane>>4) ----
    float pm = -INFINITY;
#pragma unroll
    for(int mt=0;mt<4;mt++)
#pragma unroll
      for(int r=0;r<4;r++) pm = fmaxf(pm, s[mt][r]);
    pm = fmaxf(pm, __shfl_xor(pm,16));
    pm = fmaxf(pm, __shfl_xor(pm,32));
    float mn = fmaxf(ms, pm);
    float alpha = __expf(ms - mn);
    float p[4][4];
    float rs = 0.f;
#pragma unroll
    for(int mt=0;mt<4;mt++)
#pragma unroll
      for(int r=0;r<4;r++){ float pv=__expf(s[mt][r]-mn); p[mt][r]=pv; rs+=pv; }
    rs += __shfl_xor(rs,16);
    rs += __shfl_xor(rs,32);
    ls = ls*alpha + rs; ms = mn;
#pragma unroll
    for(int mt=0;mt<4;mt++) o[mt] *= alpha;
    // ---- remap P^T into B-fragments (lane holds q=lq; needs kv=(g*8+j)+32c) ----
    bf16x8 pfh[2], pfl[2];
#pragma unroll
    for(int c=0;c<2;c++){
      u16x8 hu, lu;
#pragma unroll
      for(int j=0;j<8;j++){
        int srcLane = lq + (((g&1)*2 + (j>>2))<<4);
        float va = __shfl(p[2*c  ][j&3], srcLane);
        float vb = __shfl(p[2*c+1][j&3], srcLane);
        float v = (g>>1) ? vb : va;
        unsigned short hh, ll;
        split_bf(v, hh, ll);
        hu[j]=hh; lu[j]=ll;
      }
      pfh[c] = __builtin_bit_cast(bf16x8, hu);
      pfl[c] = __builtin_bit_cast(bf16x8, lu);
    }
    // ---- out^T += V^T . P^T  (4-term split) ----
#pragma unroll
    for(int kc=0;kc<2;kc++){
#pragma unroll
      for(int mt=0;mt<4;mt++){
        bf16x8 va_ = *(const bf16x8*)(lds + 2*8192 + LDSW(16*mt+lq, 4*kc+g));
        bf16x8 vb_ = *(const bf16x8*)(lds + 3*8192 + LDSW(16*mt+lq, 4*kc+g));
        o[mt] = __builtin_amdgcn_mfma_f32_16x16x32_bf16(va_, pfh[kc], o[mt], 0,0,0);
        o[mt] = __builtin_amdgcn_mfma_f32_16x16x32_bf16(va_, pfl[kc], o[mt], 0,0,0);
        o[mt] = __builtin_amdgcn_mfma_f32_16x16x32_bf16(vb_, pfh[kc], o[mt], 0,0,0);
        o[mt] = __builtin_amdgcn_mfma_f32_16x16x32_bf16(vb_, pfl[kc], o[mt], 0,0,0);
      }
    }
  }
  // ---- epilogue: out[q][d] = o^T / l ----
  float inv = 1.f/ls;
  float* orow = ao + (size_t)qtok*DIM + h*64;
#pragma unroll
  for(int mt=0;mt<4;mt++){
    f32x4 st = o[mt]*inv;
    *(f32x4*)(orow + mt*16 + g*4) = st;
  }
}

extern "C" void kernel_launch(void* const* d_in, const int* in_sizes, int n_in,
                              void* d_out, int out_size, void* d_ws, size_t ws_size,
                              hipStream_t stream){
  const float* x      = (const float*)d_in[0];
  const float* gamma  = (const float*)d_in[1];
  const float* beta   = (const float*)d_in[2];
  const float* w_qkv  = (const float*)d_in[3];
  const float* w_out  = (const float*)d_in[4];
  const float* b_out  = (const float*)d_in[5];
  const float* spars  = (const float*)d_in[6];
  float* out = (float*)d_out;

  // workspace layout (~201 MiB total):
  // [sums 64B pad][wq_qkv 6.75MiB][wq_out 2.25MiB][xs 48MiB (aliased by ao)]
  // [qh|ql|kh|kl 4x24MiB u16][vth|vtl 2x24MiB u16]
  double* sums  = (double*)d_ws;
  float* wq_qkv = (float*)((char*)d_ws + 64);
  float* wq_out = wq_qkv + NQKVW;
  float* xs     = wq_out + NOUTW;
  unsigned short* qh  = (unsigned short*)(xs + (size_t)TOKENS*DIM);
  unsigned short* ql  = qh  + (size_t)TOKENS*DIM;
  unsigned short* kh  = ql  + (size_t)TOKENS*DIM;
  unsigned short* kl  = kh  + (size_t)TOKENS*DIM;
  unsigned short* vth = kl  + (size_t)TOKENS*DIM;
  unsigned short* vtl = vth + (size_t)TOKENS*DIM;
  float* ao = xs;   // alias: xs dead after gemm_qkv; in-place sparsify-2 is per-row safe

  hipMemsetAsync(d_ws, 0, 16, stream);
  absmean_kernel<<<1024,256,0,stream>>>(w_qkv, NQKVW, w_out, NOUTW, sums);
  ternarize_kernel<<<(NQKVW+255)/256,256,0,stream>>>(w_qkv, NQKVW, sums, 0, wq_qkv);
  ternarize_kernel<<<(NOUTW+255)/256,256,0,stream>>>(w_out, NOUTW, sums, 1, wq_out);
  ln_sparsify_kernel<true><<<TOKENS/4,256,0,stream>>>(x, gamma, beta, spars, xs);
  gemm_qkv_kernel<<<dim3(EDIM/128, TOKENS/128),256,0,stream>>>(
      xs, wq_qkv, qh, ql, kh, kl, vth, vtl);
  attn_mfma_kernel<<<dim3(16,NHEADS,16),256,0,stream>>>(qh, ql, kh, kl, vth, vtl, ao);
  ln_sparsify_kernel<false><<<TOKENS/4,256,0,stream>>>(ao, nullptr, nullptr, spars, ao);
  gemm_out_kernel<<<dim3(DIM/128, TOKENS/128),256,0,stream>>>(
      ao, wq_out, b_out, out, TOKENS, DIM, DIM);
}

// Round 4
// 840.563 us; speedup vs baseline: 2.2067x; 1.5736x over previous
//
#include <hip/hip_runtime.h>
#include <math.h>

#define TOKENS 16384
#define DIM    768
#define EDIM   2304
#define NHEADS 12
#define DHEAD  64
#define NQKVW  (EDIM*DIM)   // 1769472
#define NOUTW  (DIM*DIM)    // 589824
#define LN_EPS 1e-5f

typedef __bf16 bf16x8 __attribute__((ext_vector_type(8)));
typedef float f32x4 __attribute__((ext_vector_type(4)));
typedef unsigned short u16x8 __attribute__((ext_vector_type(8)));
typedef unsigned short u16x4 __attribute__((ext_vector_type(4)));

// ---------------- wave reduction helpers ----------------
__device__ __forceinline__ float wsum(float v){
#pragma unroll
  for(int m=1;m<64;m<<=1) v += __shfl_xor(v,m);
  return v;
}
__device__ __forceinline__ int wsumi(int v){
#pragma unroll
  for(int m=1;m<64;m<<=1) v += __shfl_xor(v,m);
  return v;
}
__device__ __forceinline__ unsigned wminu(unsigned v){
#pragma unroll
  for(int m=1;m<64;m<<=1){ unsigned o = __shfl_xor(v,m); v = (o<v)?o:v; }
  return v;
}

// RNE float -> bf16 bits
__device__ __forceinline__ unsigned short bf_rne(float x){
  unsigned u = __float_as_uint(x);
  unsigned r = (u + 0x7FFFu + ((u>>16)&1u)) >> 16;
  return (unsigned short)r;
}
// split x = h + l (+ ~2^-17 residual), h,l bf16
__device__ __forceinline__ void split_bf(float x, unsigned short& h, unsigned short& l){
  h = bf_rne(x);
  float hf = __uint_as_float(((unsigned)h)<<16);
  l = bf_rne(x - hf);
}

// ---------------- mean(|w|) reduction for both weight tensors ----------------
__global__ __launch_bounds__(256) void absmean_kernel(
    const float* __restrict__ w1, int n1,
    const float* __restrict__ w2, int n2,
    double* __restrict__ sums){
  int stride = gridDim.x*blockDim.x;
  int i0 = blockIdx.x*blockDim.x + threadIdx.x;
  float s1=0.f, s2=0.f;
  for(int i=i0;i<n1;i+=stride) s1 += fabsf(w1[i]);
  for(int i=i0;i<n2;i+=stride) s2 += fabsf(w2[i]);
  double d1=(double)s1, d2=(double)s2;
#pragma unroll
  for(int m=1;m<64;m<<=1){ d1 += __shfl_xor(d1,m); d2 += __shfl_xor(d2,m); }
  __shared__ double l1[4], l2[4];
  int wv = threadIdx.x>>6;
  if((threadIdx.x&63)==0){ l1[wv]=d1; l2[wv]=d2; }
  __syncthreads();
  if(threadIdx.x==0){
    atomicAdd(&sums[0], l1[0]+l1[1]+l1[2]+l1[3]);
    atomicAdd(&sums[1], l2[0]+l2[1]+l2[2]+l2[3]);
  }
}

// ---------------- BitNet ternarize -> bf16 t in {-1,0,+1}; also record scale ----------------
__global__ __launch_bounds__(256) void ternarize_kernel(
    const float* __restrict__ w, int n,
    const double* __restrict__ sums, int idx,
    unsigned short* __restrict__ o, float* __restrict__ scalef){
  float s  = (float)(sums[idx]/(double)n);
  float sd = s + 1e-8f;
  int i = blockIdx.x*blockDim.x + threadIdx.x;
  if(i<n){
    float t = rintf(w[i]/sd);
    t = fminf(fmaxf(t,-1.f),1.f);
    o[i] = bf_rne(t);     // exact for -1/0/+1
  }
  if(blockIdx.x==0 && threadIdx.x==0) scalef[idx] = s;
}

// ---------------- LayerNorm (optional) + quantile sparsify; bf16 hi/lo out ----------------
template<bool DO_LN>
__global__ __launch_bounds__(256) void ln_sparsify_kernel(
    const float* __restrict__ in,
    const float* __restrict__ gamma,
    const float* __restrict__ beta,
    const float* __restrict__ qp,
    unsigned short* __restrict__ oh,
    unsigned short* __restrict__ ol){
  int token = blockIdx.x*4 + (threadIdx.x>>6);
  int lane  = threadIdx.x & 63;
  const float* row = in + (size_t)token*DIM;
  float v[12];
#pragma unroll
  for(int g=0; g<3; ++g){
    float4 t = *(const float4*)(row + g*256 + lane*4);
    v[g*4+0]=t.x; v[g*4+1]=t.y; v[g*4+2]=t.z; v[g*4+3]=t.w;
  }
  float xn[12];
  if (DO_LN){
    float s=0.f;
#pragma unroll
    for(int i=0;i<12;i++) s += v[i];
    s = wsum(s);
    float mu = s*(1.f/768.f);
    float ss=0.f;
#pragma unroll
    for(int i=0;i<12;i++){ float d=v[i]-mu; ss += d*d; }
    ss = wsum(ss);
    float inv = 1.f/sqrtf(ss*(1.f/768.f) + LN_EPS);
#pragma unroll
    for(int g=0; g<3; ++g){
      float4 gm = *(const float4*)(gamma + g*256 + lane*4);
      float4 bt = *(const float4*)(beta  + g*256 + lane*4);
      xn[g*4+0] = (v[g*4+0]-mu)*inv*gm.x + bt.x;
      xn[g*4+1] = (v[g*4+1]-mu)*inv*gm.y + bt.y;
      xn[g*4+2] = (v[g*4+2]-mu)*inv*gm.z + bt.z;
      xn[g*4+3] = (v[g*4+3]-mu)*inv*gm.w + bt.w;
    }
  } else {
#pragma unroll
    for(int i=0;i<12;i++) xn[i]=v[i];
  }
  unsigned a[12];
#pragma unroll
  for(int i=0;i<12;i++) a[i] = __float_as_uint(fabsf(xn[i]));
  float q = *qp;
  float pos = q*767.f;
  int lo = (int)floorf(pos);
  lo = lo<0 ? 0 : (lo>767 ? 767 : lo);
  float frac = pos-(float)lo;
  unsigned prefix=0;
  int r = lo;
#pragma unroll 1
  for(int bit=30; bit>=0; --bit){
    unsigned cand = prefix | (1u<<bit);
    int c=0;
#pragma unroll
    for(int i=0;i<12;i++) c += (a[i]>=prefix && a[i]<cand) ? 1 : 0;
    c = wsumi(c);
    if(r>=c){ r-=c; prefix=cand; }
  }
  float f1 = __uint_as_float(prefix);
  float thr;
  if (frac>0.f && lo<767){
    int cle=0;
#pragma unroll
    for(int i=0;i<12;i++) cle += (a[i]<=prefix)?1:0;
    cle = wsumi(cle);
    unsigned mn=0xFFFFFFFFu;
#pragma unroll
    for(int i=0;i<12;i++){ if(a[i]>prefix && a[i]<mn) mn=a[i]; }
    mn = wminu(mn);
    float f2 = (cle>=lo+2) ? f1 : __uint_as_float(mn);
    thr = (frac>=0.5f) ? f2-(f2-f1)*(1.f-frac) : f1+(f2-f1)*frac;
  } else thr=f1;
  size_t obase = (size_t)token*DIM;
#pragma unroll
  for(int g=0; g<3; ++g){
    u16x4 hv, lv;
#pragma unroll
    for(int e=0;e<4;e++){
      float val = (fabsf(xn[g*4+e])>=thr) ? xn[g*4+e] : 0.f;
      unsigned short hh, ll;
      split_bf(val, hh, ll);
      hv[e]=hh; lv[e]=ll;
    }
    *(u16x4*)(oh + obase + g*256 + lane*4) = hv;
    *(u16x4*)(ol + obase + g*256 + lane*4) = lv;
  }
}

// ---------------- split-bf16 MFMA GEMM: C = s * (Ah + Al) @ T^T ----------------
// A: 16384 x 768 (hi/lo bf16), T: N x 768 bf16 ternary. 128x128 tile, BK=64,
// 4 waves (2x2 of 64x64), 16x16x32 MFMA, XOR-swizzled LDS.
// MODE 0: N=2304, epilogue -> qh/ql/kh/kl (row-major via LDS transpose) + vth/vtl (transposed direct)
// MODE 1: N=768, epilogue -> fp32 out + bias
#define LDSW(row,c16) ((((row)*8 + ((c16) ^ ((row)&7))))*16)

template<int MODE>
__global__ __launch_bounds__(256) void gemm_sp_kernel(
    const unsigned short* __restrict__ ah, const unsigned short* __restrict__ al,
    const unsigned short* __restrict__ wt, const float* __restrict__ scalef,
    const float* __restrict__ bias,
    unsigned short* __restrict__ qh, unsigned short* __restrict__ ql,
    unsigned short* __restrict__ kh, unsigned short* __restrict__ kl,
    unsigned short* __restrict__ vth, unsigned short* __restrict__ vtl,
    float* __restrict__ outp){
  __shared__ __align__(16) char lds[49152];   // Ah | Al | B tiles, 16KB each
  const int bm = blockIdx.y*128;
  const int bn = blockIdx.x*128;
  const int tid = threadIdx.x, w = tid>>6, l = tid&63, lq = l&15, g = l>>4;
  const int wm = (w>>1)*64, wn = (w&1)*64;

  const f32x4 zero4 = {0.f,0.f,0.f,0.f};
  f32x4 acc[4][4];
#pragma unroll
  for(int mt=0;mt<4;mt++)
#pragma unroll
    for(int nt=0;nt<4;nt++) acc[mt][nt]=zero4;

#pragma unroll 1
  for(int k0=0; k0<768; k0+=64){
    __syncthreads();
    // stage Ah, Al, B tiles (each 128 rows x 64 cols bf16 = 1024 slots of 16B)
#pragma unroll
    for(int grp=0; grp<2; grp++){
      u16x8 tmp[6];
#pragma unroll
      for(int c=0;c<6;c++){
        int cc = grp*6 + c;
        int t = cc>>2;                  // 0=Ah,1=Al,2=B
        int slot = (cc&3)*256 + tid;
        int row = slot>>3, c8 = slot&7;
        int gc = ((c8 ^ (row&7)))<<3;
        const unsigned short* gp =
           (t==0) ? ah + (size_t)(bm+row)*768 + k0 + gc :
           (t==1) ? al + (size_t)(bm+row)*768 + k0 + gc :
                    wt + (size_t)(bn+row)*768 + k0 + gc;
        tmp[c] = *(const u16x8*)gp;
      }
#pragma unroll
      for(int c=0;c<6;c++){
        int cc = grp*6 + c;
        int t = cc>>2;
        int slot = (cc&3)*256 + tid;
        *(u16x8*)(lds + t*16384 + slot*16) = tmp[c];
      }
    }
    __syncthreads();
#pragma unroll
    for(int kc=0;kc<2;kc++){
      bf16x8 bfr[4];
#pragma unroll
      for(int nt=0;nt<4;nt++)
        bfr[nt] = *(const bf16x8*)(lds + 32768 + LDSW(wn+16*nt+lq, kc*4+g));
#pragma unroll
      for(int mt=0;mt<4;mt++){
        bf16x8 ahf = *(const bf16x8*)(lds +          LDSW(wm+16*mt+lq, kc*4+g));
        bf16x8 alf = *(const bf16x8*)(lds + 16384 +  LDSW(wm+16*mt+lq, kc*4+g));
#pragma unroll
        for(int nt=0;nt<4;nt++){
          acc[mt][nt] = __builtin_amdgcn_mfma_f32_16x16x32_bf16(ahf, bfr[nt], acc[mt][nt], 0,0,0);
          acc[mt][nt] = __builtin_amdgcn_mfma_f32_16x16x32_bf16(alf, bfr[nt], acc[mt][nt], 0,0,0);
        }
      }
    }
  }
  __syncthreads();   // LDS free for epilogue reuse

  if (MODE == 1){
    float s2 = scalef[1];
#pragma unroll
    for(int mt=0;mt<4;mt++)
#pragma unroll
      for(int nt=0;nt<4;nt++){
        int n = bn + wn + 16*nt + lq;
        float bs = bias[n];
#pragma unroll
        for(int r=0;r<4;r++){
          int m = bm + wm + 16*mt + 4*g + r;
          outp[(size_t)m*768 + n] = acc[mt][nt][r]*s2 + bs;
        }
      }
    return;
  }

  // MODE 0: QKV epilogue
  float s1 = scalef[0];
  if (bn < 1536){
    // Q or K region: row-major bf16 hi/lo via LDS transpose (two 64-row passes)
    const bool isQ = bn < 768;
    const float sc = isQ ? s1*0.125f : s1;
    unsigned short* dh = isQ ? qh : kh;
    unsigned short* dl = isQ ? ql : kl;
    const int cb = isQ ? bn : bn-768;
    unsigned short* Th = (unsigned short*)lds;          // [64][136]
    unsigned short* Tl = Th + 64*136;
#pragma unroll
    for(int p=0;p<2;p++){
      if(p) __syncthreads();
      if ((w>>1)==p){
#pragma unroll
        for(int mt=0;mt<4;mt++)
#pragma unroll
          for(int nt=0;nt<4;nt++)
#pragma unroll
            for(int r=0;r<4;r++){
              int mloc = 16*mt + 4*g + r;      // 0..63
              int c = wn + 16*nt + lq;         // 0..127
              unsigned short hh,ll;
              split_bf(acc[mt][nt][r]*sc, hh, ll);
              Th[mloc*136 + c] = hh;
              Tl[mloc*136 + c] = ll;
            }
      }
      __syncthreads();
      int mrow = tid>>2;             // 0..63
      int m = p*64 + mrow;
#pragma unroll
      for(int i=0;i<4;i++){
        int c8 = (tid&3)*4 + i;      // 0..15
        u16x8 hv = *(const u16x8*)(Th + mrow*136 + c8*8);
        u16x8 lv = *(const u16x8*)(Tl + mrow*136 + c8*8);
        size_t off = (size_t)(bm+m)*768 + cb + c8*8;
        *(u16x8*)(dh + off) = hv;
        *(u16x8*)(dl + off) = lv;
      }
    }
  } else {
    // V region: direct stores into transposed per-head layout [b,h,d,t]
    const int b  = bm >> 10;
    const int t0 = bm & 1023;
#pragma unroll
    for(int mt=0;mt<4;mt++)
#pragma unroll
      for(int nt=0;nt<4;nt++){
        int n = bn - 1536 + wn + 16*nt + lq;   // 0..767
        int hh_ = n>>6, d = n&63;
        u16x4 hv, lv;
#pragma unroll
        for(int r=0;r<4;r++){
          unsigned short h_, l_;
          split_bf(acc[mt][nt][r]*s1, h_, l_);
          hv[r]=h_; lv[r]=l_;
        }
        size_t off = ((size_t)(b*NHEADS + hh_)*64 + d)*1024 + t0 + wm + 16*mt + 4*g;
        *(u16x4*)(vth + off) = hv;
        *(u16x4*)(vtl + off) = lv;
      }
  }
}

// ---------------- MFMA flash attention (unchanged from round 3) ----------------
__global__ __launch_bounds__(256) void attn_mfma_kernel(
    const unsigned short* __restrict__ qh, const unsigned short* __restrict__ ql,
    const unsigned short* __restrict__ kh, const unsigned short* __restrict__ kl,
    const unsigned short* __restrict__ vh, const unsigned short* __restrict__ vl,
    float* __restrict__ ao){
  __shared__ __align__(16) char lds[32768];   // [Kh|Kl|Vh|Vl] x 8KB, swizzled 64x64 bf16 tiles
  const int qb=blockIdx.x, h=blockIdx.y, b=blockIdx.z;
  const int tid=threadIdx.x, w=tid>>6, l=tid&63, lq=l&15, g=l>>4;

  const int qtok = b*1024 + qb*64 + w*16 + lq;
  bf16x8 qhf[2], qlf[2];
  {
    const size_t qo = (size_t)qtok*768 + h*64 + g*8;
    qhf[0] = *(const bf16x8*)(qh + qo);
    qhf[1] = *(const bf16x8*)(qh + qo + 32);
    qlf[0] = *(const bf16x8*)(ql + qo);
    qlf[1] = *(const bf16x8*)(ql + qo + 32);
  }
  const f32x4 zero4 = {0.f,0.f,0.f,0.f};
  f32x4 o[4];
#pragma unroll
  for(int mt=0;mt<4;mt++) o[mt]=zero4;
  float ms = -INFINITY, ls = 0.f;

  for(int kt=0; kt<16; ++kt){
    __syncthreads();
#pragma unroll
    for(int m=0;m<4;m++){
      const unsigned short* src = (m==0)?kh:(m==1)?kl:(m==2)?vh:vl;
#pragma unroll
      for(int half=0; half<2; half++){
        int a = half*256 + tid;
        int row = a>>3;
        int c16 = (a&7)^(row&7);
        size_t goff = (m<2)
          ? ((size_t)(b*1024 + kt*64 + row)*768 + h*64 + c16*8)
          : (((size_t)(b*NHEADS + h)*64 + row)*1024 + kt*64 + c16*8);
        u16x8 v = *(const u16x8*)(src + goff);
        *(u16x8*)(lds + m*8192 + a*16) = v;
      }
    }
    __syncthreads();
    f32x4 s[4];
#pragma unroll
    for(int mt=0;mt<4;mt++) s[mt]=zero4;
#pragma unroll
    for(int kc=0;kc<2;kc++){
#pragma unroll
      for(int mt=0;mt<4;mt++){
        bf16x8 ka = *(const bf16x8*)(lds + 0*8192 + LDSW(16*mt+lq, 4*kc+g));
        bf16x8 kb = *(const bf16x8*)(lds + 1*8192 + LDSW(16*mt+lq, 4*kc+g));
        s[mt] = __builtin_amdgcn_mfma_f32_16x16x32_bf16(ka, qhf[kc], s[mt], 0,0,0);
        s[mt] = __builtin_amdgcn_mfma_f32_16x16x32_bf16(ka, qlf[kc], s[mt], 0,0,0);
        s[mt] = __builtin_amdgcn_mfma_f32_16x16x32_bf16(kb, qhf[kc], s[mt], 0,0,0);
      }
    }
    float pm = -INFINITY;
#pragma unroll
    for(int mt=0;mt<4;mt++)
#pragma unroll
      for(int r=0;r<4;r++) pm = fmaxf(pm, s[mt][r]);
    pm = fmaxf(pm, __shfl_xor(pm,16));
    pm = fmaxf(pm, __shfl_xor(pm,32));
    float mn = fmaxf(ms, pm);
    float alpha = __expf(ms - mn);
    float p[4][4];
    float rs = 0.f;
#pragma unroll
    for(int mt=0;mt<4;mt++)
#pragma unroll
      for(int r=0;r<4;r++){ float pv=__expf(s[mt][r]-mn); p[mt][r]=pv; rs+=pv; }
    rs += __shfl_xor(rs,16);
    rs += __shfl_xor(rs,32);
    ls = ls*alpha + rs; ms = mn;
#pragma unroll
    for(int mt=0;mt<4;mt++) o[mt] *= alpha;
    bf16x8 pfh[2], pfl[2];
#pragma unroll
    for(int c=0;c<2;c++){
      u16x8 hu, lu;
#pragma unroll
      for(int j=0;j<8;j++){
        int srcLane = lq + (((g&1)*2 + (j>>2))<<4);
        float va = __shfl(p[2*c  ][j&3], srcLane);
        float vb = __shfl(p[2*c+1][j&3], srcLane);
        float v = (g>>1) ? vb : va;
        unsigned short hh, ll;
        split_bf(v, hh, ll);
        hu[j]=hh; lu[j]=ll;
      }
      pfh[c] = __builtin_bit_cast(bf16x8, hu);
      pfl[c] = __builtin_bit_cast(bf16x8, lu);
    }
#pragma unroll
    for(int kc=0;kc<2;kc++){
#pragma unroll
      for(int mt=0;mt<4;mt++){
        bf16x8 va_ = *(const bf16x8*)(lds + 2*8192 + LDSW(16*mt+lq, 4*kc+g));
        bf16x8 vb_ = *(const bf16x8*)(lds + 3*8192 + LDSW(16*mt+lq, 4*kc+g));
        o[mt] = __builtin_amdgcn_mfma_f32_16x16x32_bf16(va_, pfh[kc], o[mt], 0,0,0);
        o[mt] = __builtin_amdgcn_mfma_f32_16x16x32_bf16(va_, pfl[kc], o[mt], 0,0,0);
        o[mt] = __builtin_amdgcn_mfma_f32_16x16x32_bf16(vb_, pfh[kc], o[mt], 0,0,0);
        o[mt] = __builtin_amdgcn_mfma_f32_16x16x32_bf16(vb_, pfl[kc], o[mt], 0,0,0);
      }
    }
  }
  float inv = 1.f/ls;
  float* orow = ao + (size_t)qtok*DIM + h*64;
#pragma unroll
  for(int mt=0;mt<4;mt++){
    f32x4 st = o[mt]*inv;
    *(f32x4*)(orow + mt*16 + g*4) = st;
  }
}

extern "C" void kernel_launch(void* const* d_in, const int* in_sizes, int n_in,
                              void* d_out, int out_size, void* d_ws, size_t ws_size,
                              hipStream_t stream){
  const float* x      = (const float*)d_in[0];
  const float* gamma  = (const float*)d_in[1];
  const float* beta   = (const float*)d_in[2];
  const float* w_qkv  = (const float*)d_in[3];
  const float* w_out  = (const float*)d_in[4];
  const float* b_out  = (const float*)d_in[5];
  const float* spars  = (const float*)d_in[6];
  float* out = (float*)d_out;

  // workspace (~244.5 MiB):
  // [sums 16B][scalef 8B][pad->64B][wt_qkv u16][wt_out u16][ah|al u16]
  // [qh|ql|kh|kl u16][vth|vtl u16][ao f32]
  double* sums  = (double*)d_ws;
  float* scalef = (float*)((char*)d_ws + 16);
  unsigned short* wt_qkv = (unsigned short*)((char*)d_ws + 64);
  unsigned short* wt_out = wt_qkv + NQKVW;
  unsigned short* ahb = wt_out + NOUTW;
  unsigned short* alb = ahb + (size_t)TOKENS*DIM;
  unsigned short* qh  = alb + (size_t)TOKENS*DIM;
  unsigned short* ql  = qh  + (size_t)TOKENS*DIM;
  unsigned short* kh  = ql  + (size_t)TOKENS*DIM;
  unsigned short* kl  = kh  + (size_t)TOKENS*DIM;
  unsigned short* vth = kl  + (size_t)TOKENS*DIM;
  unsigned short* vtl = vth + (size_t)TOKENS*DIM;
  float* ao = (float*)(vtl + (size_t)TOKENS*DIM);

  hipMemsetAsync(d_ws, 0, 16, stream);
  absmean_kernel<<<1024,256,0,stream>>>(w_qkv, NQKVW, w_out, NOUTW, sums);
  ternarize_kernel<<<(NQKVW+255)/256,256,0,stream>>>(w_qkv, NQKVW, sums, 0, wt_qkv, scalef);
  ternarize_kernel<<<(NOUTW+255)/256,256,0,stream>>>(w_out, NOUTW, sums, 1, wt_out, scalef);
  ln_sparsify_kernel<true><<<TOKENS/4,256,0,stream>>>(x, gamma, beta, spars, ahb, alb);
  gemm_sp_kernel<0><<<dim3(EDIM/128, TOKENS/128),256,0,stream>>>(
      ahb, alb, wt_qkv, scalef, nullptr, qh, ql, kh, kl, vth, vtl, nullptr);
  attn_mfma_kernel<<<dim3(16,NHEADS,16),256,0,stream>>>(qh, ql, kh, kl, vth, vtl, ao);
  ln_sparsify_kernel<false><<<TOKENS/4,256,0,stream>>>(ao, nullptr, nullptr, spars, ahb, alb);
  gemm_sp_kernel<1><<<dim3(DIM/128, TOKENS/128),256,0,stream>>>(
      ahb, alb, wt_out, scalef, b_out, nullptr, nullptr, nullptr, nullptr, nullptr, nullptr, out);
}

// Round 5
// 743.468 us; speedup vs baseline: 2.4949x; 1.1306x over previous
//
#include <hip/hip_runtime.h>
#include <math.h>

#define TOKENS 16384
#define DIM    768
#define EDIM   2304
#define NHEADS 12
#define DHEAD  64
#define NQKVW  (EDIM*DIM)   // 1769472
#define NOUTW  (DIM*DIM)    // 589824
#define LN_EPS 1e-5f

typedef __bf16 bf16x8 __attribute__((ext_vector_type(8)));
typedef float f32x4 __attribute__((ext_vector_type(4)));
typedef unsigned short u16x8 __attribute__((ext_vector_type(8)));
typedef unsigned short u16x4 __attribute__((ext_vector_type(4)));

// ---------------- wave reduction helpers ----------------
__device__ __forceinline__ float wsum(float v){
#pragma unroll
  for(int m=1;m<64;m<<=1) v += __shfl_xor(v,m);
  return v;
}
__device__ __forceinline__ int wsumi(int v){
#pragma unroll
  for(int m=1;m<64;m<<=1) v += __shfl_xor(v,m);
  return v;
}
__device__ __forceinline__ unsigned wminu(unsigned v){
#pragma unroll
  for(int m=1;m<64;m<<=1){ unsigned o = __shfl_xor(v,m); v = (o<v)?o:v; }
  return v;
}

// RNE split via native casts: x = h + l (+ ~2^-17 residual)
__device__ __forceinline__ void split_bf(float x, unsigned short& h, unsigned short& l){
  __bf16 hb = (__bf16)x;                       // RNE
  float hf = (float)hb;
  __bf16 lb = (__bf16)(x - hf);                // RNE
  h = __builtin_bit_cast(unsigned short, hb);
  l = __builtin_bit_cast(unsigned short, lb);
}
__device__ __forceinline__ unsigned short bf_rne(float x){
  __bf16 hb = (__bf16)x;
  return __builtin_bit_cast(unsigned short, hb);
}

// ---------------- mean(|w|) reduction for both weight tensors ----------------
__global__ __launch_bounds__(256) void absmean_kernel(
    const float* __restrict__ w1, int n1,
    const float* __restrict__ w2, int n2,
    double* __restrict__ sums){
  int stride = gridDim.x*blockDim.x;
  int i0 = blockIdx.x*blockDim.x + threadIdx.x;
  float s1=0.f, s2=0.f;
  for(int i=i0;i<n1;i+=stride) s1 += fabsf(w1[i]);
  for(int i=i0;i<n2;i+=stride) s2 += fabsf(w2[i]);
  double d1=(double)s1, d2=(double)s2;
#pragma unroll
  for(int m=1;m<64;m<<=1){ d1 += __shfl_xor(d1,m); d2 += __shfl_xor(d2,m); }
  __shared__ double l1[4], l2[4];
  int wv = threadIdx.x>>6;
  if((threadIdx.x&63)==0){ l1[wv]=d1; l2[wv]=d2; }
  __syncthreads();
  if(threadIdx.x==0){
    atomicAdd(&sums[0], l1[0]+l1[1]+l1[2]+l1[3]);
    atomicAdd(&sums[1], l2[0]+l2[1]+l2[2]+l2[3]);
  }
}

// ---------------- BitNet ternarize -> bf16 t in {-1,0,+1}; also record scale ----------------
__global__ __launch_bounds__(256) void ternarize_kernel(
    const float* __restrict__ w, int n,
    const double* __restrict__ sums, int idx,
    unsigned short* __restrict__ o, float* __restrict__ scalef){
  float s  = (float)(sums[idx]/(double)n);
  float sd = s + 1e-8f;
  int i = blockIdx.x*blockDim.x + threadIdx.x;
  if(i<n){
    float t = rintf(w[i]/sd);
    t = fminf(fmaxf(t,-1.f),1.f);
    o[i] = bf_rne(t);     // exact for -1/0/+1
  }
  if(blockIdx.x==0 && threadIdx.x==0) scalef[idx] = s;
}

// ---------------- LayerNorm (optional) + quantile sparsify; bf16 hi/lo out ----------------
template<bool DO_LN>
__global__ __launch_bounds__(256) void ln_sparsify_kernel(
    const float* __restrict__ in,
    const float* __restrict__ gamma,
    const float* __restrict__ beta,
    const float* __restrict__ qp,
    unsigned short* __restrict__ oh,
    unsigned short* __restrict__ ol){
  int token = blockIdx.x*4 + (threadIdx.x>>6);
  int lane  = threadIdx.x & 63;
  const float* row = in + (size_t)token*DIM;
  float v[12];
#pragma unroll
  for(int g=0; g<3; ++g){
    float4 t = *(const float4*)(row + g*256 + lane*4);
    v[g*4+0]=t.x; v[g*4+1]=t.y; v[g*4+2]=t.z; v[g*4+3]=t.w;
  }
  float xn[12];
  if (DO_LN){
    float s=0.f;
#pragma unroll
    for(int i=0;i<12;i++) s += v[i];
    s = wsum(s);
    float mu = s*(1.f/768.f);
    float ss=0.f;
#pragma unroll
    for(int i=0;i<12;i++){ float d=v[i]-mu; ss += d*d; }
    ss = wsum(ss);
    float inv = 1.f/sqrtf(ss*(1.f/768.f) + LN_EPS);
#pragma unroll
    for(int g=0; g<3; ++g){
      float4 gm = *(const float4*)(gamma + g*256 + lane*4);
      float4 bt = *(const float4*)(beta  + g*256 + lane*4);
      xn[g*4+0] = (v[g*4+0]-mu)*inv*gm.x + bt.x;
      xn[g*4+1] = (v[g*4+1]-mu)*inv*gm.y + bt.y;
      xn[g*4+2] = (v[g*4+2]-mu)*inv*gm.z + bt.z;
      xn[g*4+3] = (v[g*4+3]-mu)*inv*gm.w + bt.w;
    }
  } else {
#pragma unroll
    for(int i=0;i<12;i++) xn[i]=v[i];
  }
  unsigned a[12];
#pragma unroll
  for(int i=0;i<12;i++) a[i] = __float_as_uint(fabsf(xn[i]));
  float q = *qp;
  float pos = q*767.f;
  int lo = (int)floorf(pos);
  lo = lo<0 ? 0 : (lo>767 ? 767 : lo);
  float frac = pos-(float)lo;
  unsigned prefix=0;
  int r = lo;
#pragma unroll 1
  for(int bit=30; bit>=0; --bit){
    unsigned cand = prefix | (1u<<bit);
    int c=0;
#pragma unroll
    for(int i=0;i<12;i++) c += (a[i]>=prefix && a[i]<cand) ? 1 : 0;
    c = wsumi(c);
    if(r>=c){ r-=c; prefix=cand; }
  }
  float f1 = __uint_as_float(prefix);
  float thr;
  if (frac>0.f && lo<767){
    int cle=0;
#pragma unroll
    for(int i=0;i<12;i++) cle += (a[i]<=prefix)?1:0;
    cle = wsumi(cle);
    unsigned mn=0xFFFFFFFFu;
#pragma unroll
    for(int i=0;i<12;i++){ if(a[i]>prefix && a[i]<mn) mn=a[i]; }
    mn = wminu(mn);
    float f2 = (cle>=lo+2) ? f1 : __uint_as_float(mn);
    thr = (frac>=0.5f) ? f2-(f2-f1)*(1.f-frac) : f1+(f2-f1)*frac;
  } else thr=f1;
  size_t obase = (size_t)token*DIM;
#pragma unroll
  for(int g=0; g<3; ++g){
    u16x4 hv, lv;
#pragma unroll
    for(int e=0;e<4;e++){
      float val = (fabsf(xn[g*4+e])>=thr) ? xn[g*4+e] : 0.f;
      unsigned short hh, ll;
      split_bf(val, hh, ll);
      hv[e]=hh; lv[e]=ll;
    }
    *(u16x4*)(oh + obase + g*256 + lane*4) = hv;
    *(u16x4*)(ol + obase + g*256 + lane*4) = lv;
  }
}

// ---------------- split-bf16 MFMA GEMM: C = s * (Ah + Al) @ T^T ----------------
// 128x128 tile, BK=64, 4 waves, 16x16x32 MFMA, XOR-swizzled LDS, XCD-swizzled grid.
#define LDSW(row,c16) ((((row)*8 + ((c16) ^ ((row)&7))))*16)

template<int MODE>   // 0: QKV (NB=18), 1: out-proj (NB=6)
__global__ __launch_bounds__(256) void gemm_sp_kernel(
    const unsigned short* __restrict__ ah, const unsigned short* __restrict__ al,
    const unsigned short* __restrict__ wt, const float* __restrict__ scalef,
    const float* __restrict__ bias,
    unsigned short* __restrict__ qh, unsigned short* __restrict__ ql,
    unsigned short* __restrict__ kh, unsigned short* __restrict__ kl,
    unsigned short* __restrict__ vth, unsigned short* __restrict__ vtl,
    float* __restrict__ outp){
  __shared__ __align__(16) char lds[49152];   // Ah | Al | B tiles, 16KB each
  const int NB = (MODE==0) ? 18 : 6;
  const int nwg = NB*128;                     // 2304 or 768, both %8==0
  int flat = blockIdx.x;
  {
    int xcd = flat & 7, idx = flat >> 3;
    flat = xcd*(nwg>>3) + idx;                // same-XCD blocks contiguous
  }
  const int bm = (flat / NB)*128;
  const int bn = (flat % NB)*128;
  const int tid = threadIdx.x, w = tid>>6, l = tid&63, lq = l&15, g = l>>4;
  const int wm = (w>>1)*64, wn = (w&1)*64;

  const f32x4 zero4 = {0.f,0.f,0.f,0.f};
  f32x4 acc[4][4];
#pragma unroll
  for(int mt=0;mt<4;mt++)
#pragma unroll
    for(int nt=0;nt<4;nt++) acc[mt][nt]=zero4;

#pragma unroll 1
  for(int k0=0; k0<768; k0+=64){
    __syncthreads();
#pragma unroll
    for(int grp=0; grp<2; grp++){
      u16x8 tmp[6];
#pragma unroll
      for(int c=0;c<6;c++){
        int cc = grp*6 + c;
        int t = cc>>2;                  // 0=Ah,1=Al,2=B
        int slot = (cc&3)*256 + tid;
        int row = slot>>3, c8 = slot&7;
        int gc = ((c8 ^ (row&7)))<<3;
        const unsigned short* gp =
           (t==0) ? ah + (size_t)(bm+row)*768 + k0 + gc :
           (t==1) ? al + (size_t)(bm+row)*768 + k0 + gc :
                    wt + (size_t)(bn+row)*768 + k0 + gc;
        tmp[c] = *(const u16x8*)gp;
      }
#pragma unroll
      for(int c=0;c<6;c++){
        int cc = grp*6 + c;
        int t = cc>>2;
        int slot = (cc&3)*256 + tid;
        *(u16x8*)(lds + t*16384 + slot*16) = tmp[c];
      }
    }
    __syncthreads();
#pragma unroll
    for(int kc=0;kc<2;kc++){
      bf16x8 bfr[4];
#pragma unroll
      for(int nt=0;nt<4;nt++)
        bfr[nt] = *(const bf16x8*)(lds + 32768 + LDSW(wn+16*nt+lq, kc*4+g));
#pragma unroll
      for(int mt=0;mt<4;mt++){
        bf16x8 ahf = *(const bf16x8*)(lds +          LDSW(wm+16*mt+lq, kc*4+g));
        bf16x8 alf = *(const bf16x8*)(lds + 16384 +  LDSW(wm+16*mt+lq, kc*4+g));
#pragma unroll
        for(int nt=0;nt<4;nt++){
          acc[mt][nt] = __builtin_amdgcn_mfma_f32_16x16x32_bf16(ahf, bfr[nt], acc[mt][nt], 0,0,0);
          acc[mt][nt] = __builtin_amdgcn_mfma_f32_16x16x32_bf16(alf, bfr[nt], acc[mt][nt], 0,0,0);
        }
      }
    }
  }
  __syncthreads();   // LDS free for epilogue reuse

  if (MODE == 1){
    float s2 = scalef[1];
#pragma unroll
    for(int mt=0;mt<4;mt++)
#pragma unroll
      for(int nt=0;nt<4;nt++){
        int n = bn + wn + 16*nt + lq;
        float bs = bias[n];
#pragma unroll
        for(int r=0;r<4;r++){
          int m = bm + wm + 16*mt + 4*g + r;
          outp[(size_t)m*768 + n] = acc[mt][nt][r]*s2 + bs;
        }
      }
    return;
  }

  // MODE 0: QKV epilogue
  float s1 = scalef[0];
  if (bn < 1536){
    const bool isQ = bn < 768;
    const float sc = isQ ? s1*0.125f : s1;
    unsigned short* dh = isQ ? qh : kh;
    unsigned short* dl = isQ ? ql : kl;
    const int cb = isQ ? bn : bn-768;
    unsigned short* Th = (unsigned short*)lds;          // [64][136]
    unsigned short* Tl = Th + 64*136;
#pragma unroll
    for(int p=0;p<2;p++){
      if(p) __syncthreads();
      if ((w>>1)==p){
#pragma unroll
        for(int mt=0;mt<4;mt++)
#pragma unroll
          for(int nt=0;nt<4;nt++)
#pragma unroll
            for(int r=0;r<4;r++){
              int mloc = 16*mt + 4*g + r;
              int c = wn + 16*nt + lq;
              unsigned short hh,ll;
              split_bf(acc[mt][nt][r]*sc, hh, ll);
              Th[mloc*136 + c] = hh;
              Tl[mloc*136 + c] = ll;
            }
      }
      __syncthreads();
      int mrow = tid>>2;
      int m = p*64 + mrow;
#pragma unroll
      for(int i=0;i<4;i++){
        int c8 = (tid&3)*4 + i;
        u16x8 hv = *(const u16x8*)(Th + mrow*136 + c8*8);
        u16x8 lv = *(const u16x8*)(Tl + mrow*136 + c8*8);
        size_t off = (size_t)(bm+m)*768 + cb + c8*8;
        *(u16x8*)(dh + off) = hv;
        *(u16x8*)(dl + off) = lv;
      }
    }
  } else {
    const int b  = bm >> 10;
    const int t0 = bm & 1023;
#pragma unroll
    for(int mt=0;mt<4;mt++)
#pragma unroll
      for(int nt=0;nt<4;nt++){
        int n = bn - 1536 + wn + 16*nt + lq;
        int hh_ = n>>6, d = n&63;
        u16x4 hv, lv;
#pragma unroll
        for(int r=0;r<4;r++){
          unsigned short h_, l_;
          split_bf(acc[mt][nt][r]*s1, h_, l_);
          hv[r]=h_; lv[r]=l_;
        }
        size_t off = ((size_t)(b*NHEADS + hh_)*64 + d)*1024 + t0 + wm + 16*mt + 4*g;
        *(u16x4*)(vth + off) = hv;
        *(u16x4*)(vtl + off) = lv;
      }
  }
}

// ---------------- MFMA flash attention: 8 waves, QBLK=128, XCD-grouped grid ----------------
// grid: 1536 blocks 1-D. xcd = flat&7 owns 24 (b,h) pairs; 8 qb blocks per pair contiguous.
__global__ __launch_bounds__(512) void attn_mfma_kernel(
    const unsigned short* __restrict__ qh, const unsigned short* __restrict__ ql,
    const unsigned short* __restrict__ kh, const unsigned short* __restrict__ kl,
    const unsigned short* __restrict__ vh, const unsigned short* __restrict__ vl,
    float* __restrict__ ao){
  __shared__ __align__(16) char lds[32768];   // [Kh|Kl|Vh|Vl] x 8KB, swizzled 64x64 bf16 tiles
  int flat = blockIdx.x;
  int xcd = flat & 7, r_ = flat >> 3;               // r_ in [0,192)
  int pair = xcd*24 + (r_ >> 3);                    // [0,192)
  int qb = r_ & 7;
  int h = pair % NHEADS, b = pair / NHEADS;
  const int tid=threadIdx.x, w=tid>>6, l=tid&63, lq=l&15, g=l>>4;

  const int qtok = b*1024 + qb*128 + w*16 + lq;
  bf16x8 qhf[2], qlf[2];
  {
    const size_t qo = (size_t)qtok*768 + h*64 + g*8;
    qhf[0] = *(const bf16x8*)(qh + qo);
    qhf[1] = *(const bf16x8*)(qh + qo + 32);
    qlf[0] = *(const bf16x8*)(ql + qo);
    qlf[1] = *(const bf16x8*)(ql + qo + 32);
  }
  const f32x4 zero4 = {0.f,0.f,0.f,0.f};
  f32x4 o[4];
#pragma unroll
  for(int mt=0;mt<4;mt++) o[mt]=zero4;
  float ms = -INFINITY, ls = 0.f;

#pragma unroll 1
  for(int kt=0; kt<16; ++kt){
    __syncthreads();
    // stage Kh,Kl,Vh,Vl tiles (512 slots each, one slot per thread per tile)
    {
      int a = tid;                       // 0..511
      int row = a>>3;
      int c16 = (a&7)^(row&7);
      size_t koff = (size_t)(b*1024 + kt*64 + row)*768 + h*64 + c16*8;
      size_t voff = ((size_t)(b*NHEADS + h)*64 + row)*1024 + kt*64 + c16*8;
      u16x8 v0 = *(const u16x8*)(kh + koff);
      u16x8 v1 = *(const u16x8*)(kl + koff);
      u16x8 v2 = *(const u16x8*)(vh + voff);
      u16x8 v3 = *(const u16x8*)(vl + voff);
      *(u16x8*)(lds + 0*8192 + a*16) = v0;
      *(u16x8*)(lds + 1*8192 + a*16) = v1;
      *(u16x8*)(lds + 2*8192 + a*16) = v2;
      *(u16x8*)(lds + 3*8192 + a*16) = v3;
    }
    __syncthreads();
    f32x4 s[4];
#pragma unroll
    for(int mt=0;mt<4;mt++) s[mt]=zero4;
#pragma unroll
    for(int kc=0;kc<2;kc++){
#pragma unroll
      for(int mt=0;mt<4;mt++){
        bf16x8 ka = *(const bf16x8*)(lds + 0*8192 + LDSW(16*mt+lq, 4*kc+g));
        bf16x8 kb = *(const bf16x8*)(lds + 1*8192 + LDSW(16*mt+lq, 4*kc+g));
        s[mt] = __builtin_amdgcn_mfma_f32_16x16x32_bf16(ka, qhf[kc], s[mt], 0,0,0);
        s[mt] = __builtin_amdgcn_mfma_f32_16x16x32_bf16(ka, qlf[kc], s[mt], 0,0,0);
        s[mt] = __builtin_amdgcn_mfma_f32_16x16x32_bf16(kb, qhf[kc], s[mt], 0,0,0);
      }
    }
    float pm = -INFINITY;
#pragma unroll
    for(int mt=0;mt<4;mt++)
#pragma unroll
      for(int r=0;r<4;r++) pm = fmaxf(pm, s[mt][r]);
    pm = fmaxf(pm, __shfl_xor(pm,16));
    pm = fmaxf(pm, __shfl_xor(pm,32));
    float mn = fmaxf(ms, pm);
    float alpha = __expf(ms - mn);
    float p[4][4];
    float rs = 0.f;
#pragma unroll
    for(int mt=0;mt<4;mt++)
#pragma unroll
      for(int r=0;r<4;r++){ float pv=__expf(s[mt][r]-mn); p[mt][r]=pv; rs+=pv; }
    rs += __shfl_xor(rs,16);
    rs += __shfl_xor(rs,32);
    ls = ls*alpha + rs; ms = mn;
#pragma unroll
    for(int mt=0;mt<4;mt++) o[mt] *= alpha;
    bf16x8 pfh[2], pfl[2];
#pragma unroll
    for(int c=0;c<2;c++){
      u16x8 hu, lu;
#pragma unroll
      for(int j=0;j<8;j++){
        int srcLane = lq + (((g&1)*2 + (j>>2))<<4);
        float va = __shfl(p[2*c  ][j&3], srcLane);
        float vb = __shfl(p[2*c+1][j&3], srcLane);
        float v = (g>>1) ? vb : va;
        unsigned short hh, ll;
        split_bf(v, hh, ll);
        hu[j]=hh; lu[j]=ll;
      }
      pfh[c] = __builtin_bit_cast(bf16x8, hu);
      pfl[c] = __builtin_bit_cast(bf16x8, lu);
    }
#pragma unroll
    for(int kc=0;kc<2;kc++){
#pragma unroll
      for(int mt=0;mt<4;mt++){
        bf16x8 va_ = *(const bf16x8*)(lds + 2*8192 + LDSW(16*mt+lq, 4*kc+g));
        bf16x8 vb_ = *(const bf16x8*)(lds + 3*8192 + LDSW(16*mt+lq, 4*kc+g));
        o[mt] = __builtin_amdgcn_mfma_f32_16x16x32_bf16(va_, pfh[kc], o[mt], 0,0,0);
        o[mt] = __builtin_amdgcn_mfma_f32_16x16x32_bf16(va_, pfl[kc], o[mt], 0,0,0);
        o[mt] = __builtin_amdgcn_mfma_f32_16x16x32_bf16(vb_, pfh[kc], o[mt], 0,0,0);
        o[mt] = __builtin_amdgcn_mfma_f32_16x16x32_bf16(vb_, pfl[kc], o[mt], 0,0,0);
      }
    }
  }
  float inv = 1.f/ls;
  float* orow = ao + (size_t)qtok*DIM + h*64;
#pragma unroll
  for(int mt=0;mt<4;mt++){
    f32x4 st = o[mt]*inv;
    *(f32x4*)(orow + mt*16 + g*4) = st;
  }
}

extern "C" void kernel_launch(void* const* d_in, const int* in_sizes, int n_in,
                              void* d_out, int out_size, void* d_ws, size_t ws_size,
                              hipStream_t stream){
  const float* x      = (const float*)d_in[0];
  const float* gamma  = (const float*)d_in[1];
  const float* beta   = (const float*)d_in[2];
  const float* w_qkv  = (const float*)d_in[3];
  const float* w_out  = (const float*)d_in[4];
  const float* b_out  = (const float*)d_in[5];
  const float* spars  = (const float*)d_in[6];
  float* out = (float*)d_out;

  double* sums  = (double*)d_ws;
  float* scalef = (float*)((char*)d_ws + 16);
  unsigned short* wt_qkv = (unsigned short*)((char*)d_ws + 64);
  unsigned short* wt_out = wt_qkv + NQKVW;
  unsigned short* ahb = wt_out + NOUTW;
  unsigned short* alb = ahb + (size_t)TOKENS*DIM;
  unsigned short* qh  = alb + (size_t)TOKENS*DIM;
  unsigned short* ql  = qh  + (size_t)TOKENS*DIM;
  unsigned short* kh  = ql  + (size_t)TOKENS*DIM;
  unsigned short* kl  = kh  + (size_t)TOKENS*DIM;
  unsigned short* vth = kl  + (size_t)TOKENS*DIM;
  unsigned short* vtl = vth + (size_t)TOKENS*DIM;
  float* ao = (float*)(vtl + (size_t)TOKENS*DIM);

  hipMemsetAsync(d_ws, 0, 16, stream);
  absmean_kernel<<<1024,256,0,stream>>>(w_qkv, NQKVW, w_out, NOUTW, sums);
  ternarize_kernel<<<(NQKVW+255)/256,256,0,stream>>>(w_qkv, NQKVW, sums, 0, wt_qkv, scalef);
  ternarize_kernel<<<(NOUTW+255)/256,256,0,stream>>>(w_out, NOUTW, sums, 1, wt_out, scalef);
  ln_sparsify_kernel<true><<<TOKENS/4,256,0,stream>>>(x, gamma, beta, spars, ahb, alb);
  gemm_sp_kernel<0><<<2304,256,0,stream>>>(
      ahb, alb, wt_qkv, scalef, nullptr, qh, ql, kh, kl, vth, vtl, nullptr);
  attn_mfma_kernel<<<1536,512,0,stream>>>(qh, ql, kh, kl, vth, vtl, ao);
  ln_sparsify_kernel<false><<<TOKENS/4,256,0,stream>>>(ao, nullptr, nullptr, spars, ahb, alb);
  gemm_sp_kernel<1><<<768,256,0,stream>>>(
      ahb, alb, wt_out, scalef, b_out, nullptr, nullptr, nullptr, nullptr, nullptr, nullptr, out);
}